// Round 12
// baseline (128.709 us; speedup 1.0000x reference)
//
#include <hip/hip_runtime.h>
#include <cstdint>
#include <cstddef>

#define DEVINL __device__ __forceinline__

static constexpr int Bdim = 2, Ldim = 32, Cdim = 128, Hdim = 32, Wdim = 32;
static constexpr int HW  = Hdim * Wdim;         // 1024
static constexpr int CHW = Cdim * HW;           // 131072
static constexpr size_t BCHW = (size_t)Bdim * CHW;               // 262144
static constexpr size_t OUT0_ELEMS = (size_t)Bdim * Ldim * CHW;  // 8388608
static constexpr size_t OUT1_CPLX  = (size_t)Bdim * CHW;         // 262144 complex elems

typedef __attribute__((ext_vector_type(8))) short short8v;   // 8 bf16 (4 VGPR)
typedef __attribute__((ext_vector_type(4))) float f32x4;     // MFMA C/D

DEVINL int bitrev5(int v) {
    return ((v&1)<<4) | ((v&2)<<2) | (v&4) | ((v&8)>>2) | ((v&16)>>4);
}
DEVINL unsigned short f2bf(float v) {               // RNE f32 -> bf16 bits
    unsigned u = __float_as_uint(v);
    return (unsigned short)((u + 0x7FFFu + ((u >> 16) & 1u)) >> 16);
}
DEVINL void bfsplit(float v, short& hi, short& lo) {
    unsigned short hb = f2bf(v);
    hi = (short)hb;
    float hf = __uint_as_float(((unsigned)hb) << 16);
    lo = (short)f2bf(v - hf);
}
DEVINL unsigned pack2bf(float2 v) {
    return (unsigned)f2bf(v.x) | ((unsigned)f2bf(v.y) << 16);
}
DEVINL float2 unpack2bf(unsigned u) {
    return make_float2(__uint_as_float(u << 16), __uint_as_float(u & 0xFFFF0000u));
}

// ================= 32-point radix-2 DIT FFT, fully in registers =================
template<int INV>
DEVINL void fft32_reg(float2 v[32]) {
    constexpr float TC[16] = { 1.0f, 0.980785280f, 0.923879533f, 0.831469612f,
                               0.707106781f, 0.555570233f, 0.382683432f, 0.195090322f,
                               0.0f, -0.195090322f, -0.382683432f, -0.555570233f,
                              -0.707106781f, -0.831469612f, -0.923879533f, -0.980785280f };
    constexpr float TS[16] = { 0.0f, -0.195090322f, -0.382683432f, -0.555570233f,
                              -0.707106781f, -0.831469612f, -0.923879533f, -0.980785280f,
                              -1.0f, -0.980785280f, -0.923879533f, -0.831469612f,
                              -0.707106781f, -0.555570233f, -0.382683432f, -0.195090322f };
#pragma unroll
    for (int st = 0; st < 5; ++st) {
        const int half = 1 << st;
#pragma unroll
        for (int bf = 0; bf < 16; ++bf) {
            const int g = bf >> st;
            const int j = bf & (half - 1);
            const int i0 = (g << (st+1)) + j;
            const float wr = TC[j << (4-st)];
            const float wi = INV ? -TS[j << (4-st)] : TS[j << (4-st)];
            float2 a0 = v[i0], a1 = v[i0+half];
            float tr = wr*a1.x - wi*a1.y;
            float ti = wr*a1.y + wi*a1.x;
            v[i0]      = make_float2(a0.x+tr, a0.y+ti);
            v[i0+half] = make_float2(a0.x-tr, a0.y-ti);
        }
    }
}

// ---- forward FFT along H (real f32 input) -> plain bf16x2 [b][l][c][hf][w] ----
__global__ __launch_bounds__(256) void fft_h_fwd_bf_kernel(const float* __restrict__ x,
                                                           unsigned* __restrict__ Hf) {
    const int gid = blockIdx.x*256 + threadIdx.x;     // 0..262143
    const int w = gid & 31;
    const size_t slice = (size_t)(gid >> 5);          // (b,l,c)
    const float* src = x + slice*HW + w;
    float2 v[32];
#pragma unroll
    for (int i = 0; i < 32; ++i)
        v[i] = make_float2(src[(size_t)bitrev5(i)*Wdim], 0.f);
    fft32_reg<0>(v);
    unsigned* dst = Hf + slice*HW + w;
#pragma unroll
    for (int h = 0; h < 32; ++h) dst[(size_t)h*Wdim] = pack2bf(v[h]);
}

// ---- forward FFT along W for out1 (l=31 freq state, f32) ----
template<int CPLX>
__global__ __launch_bounds__(256) void fft_w_out1_kernel(const float2* __restrict__ st31,
                                                         float* __restrict__ out1) {
    const int row = blockIdx.x*256 + threadIdx.x;   // 0..8191 = (b,c,h)
    const float2* src = st31 + (size_t)row*32;
    float2 v[32];
#pragma unroll
    for (int i = 0; i < 32; ++i) v[i] = src[bitrev5(i)];
    fft32_reg<0>(v);
    if (CPLX) {
        float2* dst = reinterpret_cast<float2*>(out1) + (size_t)row*32;
#pragma unroll
        for (int i = 0; i < 32; ++i) dst[i] = v[i];
    } else {
        float* dst = out1 + (size_t)row*32;
#pragma unroll
        for (int i = 0; i < 32; ++i) dst[i] = v[i].x;
    }
}

// ======================= A-pack (unchanged, verified) ==========
__global__ __launch_bounds__(256) void pack_w_kernel(
    const float* __restrict__ Wb_re, const float* __restrict__ Wb_im,
    const float* __restrict__ Wc_re, const float* __restrict__ Wc_im,
    short* __restrict__ Apack)
{
    const int gid = blockIdx.x*256 + threadIdx.x;    // 0..12287
    const int a    = gid >> 12;
    const int rem  = gid & 4095;
    const int f    = rem >> 6;
    const int lane = rem & 63;
    const int m  = f >> 3, kc = f & 7;
    const int row = m*16 + (lane & 15);
    const int kbase = kc*32 + ((lane >> 4) << 3);
    short8v hi8, lo8;
#pragma unroll
    for (int j = 0; j < 8; ++j) {
        const int k = kbase + j;
        const int half = k >> 7;
        const int c = k & 127;
        float v;
        if (a == 0)      v = half ? -Wb_im[row*Cdim + c] : Wb_re[row*Cdim + c];
        else if (a == 1) v = half ?  Wb_re[row*Cdim + c] : Wb_im[row*Cdim + c];
        else             v = half ? -Wc_im[row*Cdim + c] : Wc_re[row*Cdim + c];
        short h, l; bfsplit(v, h, l);
        hi8[j] = h; lo8[j] = l;
    }
    const size_t off = (size_t)(f*64 + lane)*8;
    *reinterpret_cast<short8v*>(Apack + (size_t)(2*a)  *32768 + off) = hi8;
    *reinterpret_cast<short8v*>(Apack + (size_t)(2*a+1)*32768 + off) = lo8;
}

// ======================= MFMA channel mix v3: plain bf16x2 input (verified r9) ====
template<int MODE>
__global__ __launch_bounds__(256) void mix_mfma3_kernel(
    const unsigned* __restrict__ Yin,
    unsigned* __restrict__ Sout,
    const short* __restrict__ Apack,
    const float* __restrict__ bre, const float* __restrict__ bim,
    const float* __restrict__ pl,
    unsigned short* __restrict__ outr,
    float2* __restrict__ lnpart)
{
    __shared__ short Bs[8][4][64][8];    // 32 KB
    const int bx = blockIdx.x;           // 64 bl * 16 tt
    const int bl = bx >> 4, tt = bx & 15;
    const int t = threadIdx.x;
    const int wv = t >> 6, lane = t & 63;

    // ---- stage: coalesced loads + lo/hi de-interleave into fragments ----
    const unsigned* src = Yin + (size_t)bl*CHW + tt*64;
#pragma unroll
    for (int g = 0; g < 4; ++g) {
        const int id = g*256 + t;          // 1024 groups of 8 channels
        const int hw = id & 63;
        const int co = id >> 6;            // channel octet 0..15 (c = co*8+j)
        const int kc = co >> 2;
        const int ln = (co & 3)*16 + (hw & 15);
        const int nt4 = hw >> 4;
        unsigned u[8];
#pragma unroll
        for (int j = 0; j < 8; ++j)
            u[j] = src[(size_t)(co*8 + j)*HW + hw];
        unsigned re[4], im[4];
#pragma unroll
        for (int p = 0; p < 4; ++p) {
            re[p] = (u[2*p] & 0xFFFFu) | (u[2*p+1] << 16);
            im[p] = (u[2*p] >> 16) | (u[2*p+1] & 0xFFFF0000u);
        }
        *reinterpret_cast<uint4*>(&Bs[kc][nt4][ln][0])   = make_uint4(re[0], re[1], re[2], re[3]);
        *reinterpret_cast<uint4*>(&Bs[kc+4][nt4][ln][0]) = make_uint4(im[0], im[1], im[2], im[3]);
    }
    __syncthreads();

    f32x4 accRe[2][4];
    f32x4 accIm[2][4];
#pragma unroll
    for (int mi = 0; mi < 2; ++mi)
#pragma unroll
        for (int nt = 0; nt < 4; ++nt) {
            accRe[mi][nt] = (f32x4)(0.0f);
            accIm[mi][nt] = (f32x4)(0.0f);
        }

    const short* Are_hi = Apack + (MODE == 0 ? 0 : 4)*32768;
    const short* Are_lo = Are_hi + 32768;
    const short* Aim_hi = Apack + 2*32768;   // MODE 0 only
    const short* Aim_lo = Aim_hi + 32768;

#pragma unroll 2
    for (int kc = 0; kc < 8; ++kc) {
        short8v bh[4];
#pragma unroll
        for (int nt = 0; nt < 4; ++nt)
            bh[nt] = *reinterpret_cast<const short8v*>(&Bs[kc][nt][lane][0]);
#pragma unroll
        for (int mi = 0; mi < 2; ++mi) {
            const int m = wv*2 + mi;
            const size_t off = (size_t)((m*8 + kc)*64 + lane)*8;
            const short8v arh = *reinterpret_cast<const short8v*>(Are_hi + off);
            const short8v arl = *reinterpret_cast<const short8v*>(Are_lo + off);
#pragma unroll
            for (int nt = 0; nt < 4; ++nt) {
                accRe[mi][nt] = __builtin_amdgcn_mfma_f32_16x16x32_bf16(arh, bh[nt], accRe[mi][nt], 0, 0, 0);
                accRe[mi][nt] = __builtin_amdgcn_mfma_f32_16x16x32_bf16(arl, bh[nt], accRe[mi][nt], 0, 0, 0);
            }
            if (MODE == 0) {
                const short8v aih = *reinterpret_cast<const short8v*>(Aim_hi + off);
                const short8v ail = *reinterpret_cast<const short8v*>(Aim_lo + off);
#pragma unroll
                for (int nt = 0; nt < 4; ++nt) {
                    accIm[mi][nt] = __builtin_amdgcn_mfma_f32_16x16x32_bf16(aih, bh[nt], accIm[mi][nt], 0, 0, 0);
                    accIm[mi][nt] = __builtin_amdgcn_mfma_f32_16x16x32_bf16(ail, bh[nt], accIm[mi][nt], 0, 0, 0);
                }
            }
        }
    }

    // ---- epilogue.  D layout: col = lane&15, row = (lane>>4)*4 + r ----
    const int col   = lane & 15;
    const int rbase = (lane >> 4) * 4;
    float lns = 0.f, lnq = 0.f;
#pragma unroll
    for (int mi = 0; mi < 2; ++mi) {
#pragma unroll
        for (int r = 0; r < 4; ++r) {
            const int o = wv*32 + mi*16 + rbase + r;
            if (MODE == 0) {
                const float br = bre[o], bi = bim[o];
                const float g0 = expf(pl[(2*Cdim + o)*Hdim + 2*tt]);
                const float g1 = expf(pl[(2*Cdim + o)*Hdim + 2*tt + 1]);
#pragma unroll
                for (int nt = 0; nt < 4; ++nt) {
                    const int wcol = nt*16 + col;
                    const float g = (nt < 2) ? g0 : g1;
                    const float bsel = ((wcol & 31) == 0) ? 1.0f : 0.0f;
                    float2 rv;
                    rv.x = (accRe[mi][nt][r] + br*bsel) * g;
                    rv.y = (accIm[mi][nt][r] + bi*bsel) * g;
                    Sout[(size_t)bl*CHW + (size_t)o*HW + tt*64 + wcol] = pack2bf(rv);
                }
            } else {
                const float br = bre[o];
#pragma unroll
                for (int nt = 0; nt < 4; ++nt) {
                    const int wcol = nt*16 + col;
                    const float v = accRe[mi][nt][r] + br;
                    outr[(size_t)bl*CHW + (size_t)o*HW + tt*64 + wcol] = f2bf(v);
                    lns += v; lnq += v*v;
                }
            }
        }
    }
    if (MODE == 1) {
#pragma unroll
        for (int off = 32; off > 0; off >>= 1) {
            lns += __shfl_down(lns, off);
            lnq += __shfl_down(lnq, off);
        }
        __shared__ float2 red[4];
        if (lane == 0) red[wv] = make_float2(lns, lnq);
        __syncthreads();
        if (t == 0) {
            float2 a = red[0], b2 = red[1], c2 = red[2], d = red[3];
            lnpart[bx] = make_float2(a.x + b2.x + c2.x + d.x, a.y + b2.y + c2.y + d.y);
        }
    }
}

// ======================= scan pass 1: boundary carries ==========================
// One thread per (b, chw) column; serial scan l = 0..23 of the bf16x2 input,
// stores y after l=7,15,23 -> carry[k][b][chw], k = 0,1,2.  f32 state.
__global__ __launch_bounds__(256) void scan_carry_kernel(
    const unsigned* __restrict__ Sin, const float* __restrict__ pl,
    float2* __restrict__ carry)
{
    const int idx = blockIdx.x*256 + threadIdx.x;   // 0..262143
    const int b   = idx >> 17;
    const int chw = idx & (CHW - 1);
    const int c   = chw >> 10;
    const int h   = (chw >> 5) & 31;
    const float nu = expf(pl[c*Hdim + h]);
    const float th = expf(pl[(Cdim + c)*Hdim + h]);
    const float rr = expf(-nu);
    const float lr = rr * cosf(th);
    const float li = rr * sinf(th);
    float2 y = make_float2(0.f, 0.f);
    const size_t basei = (size_t)b * Ldim * CHW + chw;
#pragma unroll 4
    for (int l = 0; l < 24; ++l) {
        float2 hv = unpack2bf(Sin[basei + (size_t)l*CHW]);
        float yr = fmaf(lr, y.x, fmaf(-li, y.y, hv.x));
        float yi = fmaf(lr, y.y, fmaf( li, y.x, hv.y));
        y = make_float2(yr, yi);
        if (l == 7)  carry[0*BCHW + (size_t)b*CHW + chw] = y;
        if (l == 15) carry[1*BCHW + (size_t)b*CHW + chw] = y;
        if (l == 23) carry[2*BCHW + (size_t)b*CHW + chw] = y;
    }
}

// ======================= scan pass 2: segment scan + inverse-FFT ==================
// Block = (b, c, wh, seg): seg owns l in [seg*8, seg*8+8), carry-in from pass 1.
// Thread owns slots a0 = t>>4 and a0+16 at col = t&15 (freq bins hb0, hb0+1).
// Same verified butterfly body as round 11.  Grid 2048.
__global__ __launch_bounds__(256) void scan_ifft_seg_kernel(
    const unsigned* __restrict__ Sin,   // [b][l][c][hf][w] bf16x2
    unsigned* __restrict__ Ysp,         // [b][l][c][h][w]  bf16x2
    const float* __restrict__ pl,
    const float2* __restrict__ carry,   // [3][b][chw]
    float2* __restrict__ st31)          // [b][c][hf][w] f32 complex
{
    __shared__ float2 sh[32][17];       // 4352 B
    __shared__ float2 tw[16];
    const int blk = blockIdx.x;         // (((b*128)+c)*2 + wh)*4 + seg
    const int seg = blk & 3;
    const int wh  = (blk >> 3) & 1;     // note: bits [3], seg bits [0:1], spare bit2
    const int c   = (blk >> 4) & 127;
    const int b   = blk >> 11;
    const int t = threadIdx.x;
    const int col = t & 15;
    const int a0 = t >> 4;              // slots a0 and a0+16
    const int w = wh*16 + col;
    if (t < 16) {
        float ang = -6.283185307179586f * (float)t / 32.0f;
        tw[t] = make_float2(cosf(ang), sinf(ang));
    }
    const int hb0 = bitrev5(a0);        // hb(a0+16) == hb0 + 1
    const float nu0 = expf(pl[c*Hdim + hb0]);
    const float th0 = expf(pl[(Cdim + c)*Hdim + hb0]);
    const float r0  = expf(-nu0);
    const float2 lam0 = make_float2(r0*cosf(th0), r0*sinf(th0));
    const float nu1 = expf(pl[c*Hdim + hb0 + 1]);
    const float th1 = expf(pl[(Cdim + c)*Hdim + hb0 + 1]);
    const float r1  = expf(-nu1);
    const float2 lam1 = make_float2(r1*cosf(th1), r1*sinf(th1));
    float2 y0 = make_float2(0.f, 0.f);
    float2 y1 = make_float2(0.f, 0.f);
    if (seg > 0) {
        const float2* cp = carry + (size_t)(seg-1)*BCHW + (size_t)b*CHW
                         + (size_t)c*HW;
        y0 = cp[hb0*Wdim + w];
        y1 = cp[(hb0+1)*Wdim + w];
    }
    const float sc = 1.0f / 32.0f;
    __syncthreads();                     // tw ready

    const int l0 = seg*8, l1 = l0 + 8;
    const size_t cbase = ((size_t)(b*Ldim)*Cdim + c)*HW;
    unsigned nxt0 = Sin[cbase + (size_t)l0*CHW + (size_t)hb0*Wdim + w];
    unsigned nxt1 = Sin[cbase + (size_t)l0*CHW + (size_t)(hb0+1)*Wdim + w];

    for (int l = l0; l < l1; ++l) {
        const size_t base = cbase + (size_t)l*CHW;
        const float2 hv0 = unpack2bf(nxt0);
        const float2 hv1 = unpack2bf(nxt1);
        if (l < l1 - 1) {                // prefetch next l (hidden under butterflies)
            nxt0 = Sin[base + CHW + (size_t)hb0*Wdim + w];
            nxt1 = Sin[base + CHW + (size_t)(hb0+1)*Wdim + w];
        }
        // scan updates (own freq bins)
        y0 = make_float2(fmaf(lam0.x, y0.x, fmaf(-lam0.y, y0.y, hv0.x)),
                         fmaf(lam0.x, y0.y, fmaf( lam0.y, y0.x, hv0.y)));
        y1 = make_float2(fmaf(lam1.x, y1.x, fmaf(-lam1.y, y1.y, hv1.x)),
                         fmaf(lam1.x, y1.y, fmaf( lam1.y, y1.x, hv1.y)));
        sh[a0][col]      = y0;
        sh[a0 + 16][col] = y1;
        __syncthreads();
        // 5 inverse butterfly stages: 16 bf x 16 cols = 256 tasks, all threads
#pragma unroll
        for (int st = 0; st < 5; ++st) {
            const int half = 1 << st;
            const int bf = t >> 4;           // 0..15
            const int g = bf >> st;
            const int j = bf & (half - 1);
            const int i0 = (g << (st+1)) + j;
            float2 tww = tw[j << (4-st)];
            tww.y = -tww.y;                  // inverse FFT
            float2 u0 = sh[i0][col];
            float2 u1 = sh[i0 + half][col];
            float tr = tww.x*u1.x - tww.y*u1.y;
            float ti = tww.x*u1.y + tww.y*u1.x;
            sh[i0][col]        = make_float2(u0.x + tr, u0.y + ti);
            sh[i0 + half][col] = make_float2(u0.x - tr, u0.y - ti);
            __syncthreads();
        }
        // read own slots (stage 4 wrote exactly slots a0, a0+16 from this thread)
        float2 v0 = sh[a0][col];
        float2 v1 = sh[a0 + 16][col];
        Ysp[base + (size_t)a0*Wdim + w]        = pack2bf(make_float2(v0.x*sc, v0.y*sc));
        Ysp[base + (size_t)(a0+16)*Wdim + w]   = pack2bf(make_float2(v1.x*sc, v1.y*sc));
    }
    if (seg == 3) {
        const size_t obase = ((size_t)b*Cdim + c)*HW;
        st31[obase + (size_t)hb0*Wdim + w]     = y0;
        st31[obase + (size_t)(hb0+1)*Wdim + w] = y1;
    }
}

// ======================= LayerNorm finish + apply =======================
__global__ __launch_bounds__(64) void ln_finish_kernel(const float2* __restrict__ lnpart,
                                                       float2* __restrict__ stats) {
    const int bl = blockIdx.x;
    const int t = threadIdx.x;
    float s = 0.f, sq = 0.f;
    if (t < 16) { float2 v = lnpart[bl*16 + t]; s = v.x; sq = v.y; }
#pragma unroll
    for (int off = 8; off > 0; off >>= 1) {
        s  += __shfl_down(s, off);
        sq += __shfl_down(sq, off);
    }
    if (t == 0) {
        const float invN = 1.0f / (float)CHW;
        float mean = s * invN;
        float var  = sq * invN - mean*mean;
        stats[bl] = make_float2(mean, rsqrtf(var + 1e-5f));
    }
}

__global__ __launch_bounds__(256) void ln_apply_kernel(
    float* __restrict__ out0, const unsigned short* __restrict__ hpre,
    const float* __restrict__ x,
    const float* __restrict__ lnw, const float* __restrict__ lnb,
    const float2* __restrict__ stats)
{
    const int idx4 = blockIdx.x*256 + threadIdx.x;   // 4 elems per thread
    const int i = idx4 * 4;
    const int bl = i >> 17;
    const int chw4 = (i & (CHW - 1)) >> 2;
    const float2 st = stats[bl];
    const uint2 hu = reinterpret_cast<const uint2*>(hpre)[idx4];
    float4 h;
    h.x = __uint_as_float(hu.x << 16);
    h.y = __uint_as_float(hu.x & 0xFFFF0000u);
    h.z = __uint_as_float(hu.y << 16);
    h.w = __uint_as_float(hu.y & 0xFFFF0000u);
    float4 xv = reinterpret_cast<const float4*>(x)[idx4];
    float4 w  = reinterpret_cast<const float4*>(lnw)[chw4];
    float4 bb = reinterpret_cast<const float4*>(lnb)[chw4];
    const float m = st.x, rs = st.y;
    float4 r;
    r.x = fmaf((h.x - m)*rs, w.x, bb.x) + xv.x;
    r.y = fmaf((h.y - m)*rs, w.y, bb.y) + xv.y;
    r.z = fmaf((h.z - m)*rs, w.z, bb.z) + xv.z;
    r.w = fmaf((h.w - m)*rs, w.w, bb.w) + xv.w;
    reinterpret_cast<float4*>(out0)[idx4] = r;
}

// ======================= launch =======================
extern "C" void kernel_launch(void* const* d_in, const int* in_sizes, int n_in,
                              void* d_out, int out_size, void* d_ws, size_t ws_size,
                              hipStream_t stream)
{
    const float* x     = (const float*)d_in[0];
    const float* pl    = (const float*)d_in[1];
    const float* Wb_re = (const float*)d_in[2];
    const float* Wb_im = (const float*)d_in[3];
    const float* bb_re = (const float*)d_in[4];
    const float* bb_im = (const float*)d_in[5];
    const float* Wc_re = (const float*)d_in[6];
    const float* Wc_im = (const float*)d_in[7];
    const float* bc_re = (const float*)d_in[8];
    const float* bc_im = (const float*)d_in[9];
    const float* ln_w  = (const float*)d_in[10];
    const float* ln_b  = (const float*)d_in[11];

    float* out0 = (float*)d_out;
    float* out1 = out0 + OUT0_ELEMS;

    // workspace layout (~92.7 MB; rounds 7-11 proved ws >= 103 MB)
    char* ws = (char*)d_ws;
    unsigned*       bufA    = (unsigned*)       ws;                        // 33,554,432 (Hf_freq, later Ysp)
    unsigned*       bufB    = (unsigned*)       (ws + 33554432);           // 33,554,432 (scan input)
    unsigned short* out0pre = (unsigned short*) (ws + 67108864);           // 16,777,216
    float2*         st31    = (float2*)         (ws + 83886080);           //  2,097,152
    short*          Apack   = (short*)          (ws + 85983232);           //    393,216
    float2*         lnpart  = (float2*)         (ws + 86376448);           //      8,192
    float2*         stats   = (float2*)         (ws + 86384640);           //        512
    float2*         carry   = (float2*)         (ws + 86385152);           //  6,291,456

    const bool interleaved = ((size_t)out_size >= OUT0_ELEMS + 2*OUT1_CPLX);

    pack_w_kernel<<<48, 256, 0, stream>>>(Wb_re, Wb_im, Wc_re, Wc_im, Apack);
    fft_h_fwd_bf_kernel<<<1024, 256, 0, stream>>>(x, bufA);
    mix_mfma3_kernel<0><<<1024, 256, 0, stream>>>(bufA, bufB, Apack, bb_re, bb_im, pl, nullptr, nullptr);
    scan_carry_kernel<<<1024, 256, 0, stream>>>(bufB, pl, carry);
    // grid: (((b*128)+c)*2 + wh) in bits >=3, spare bit2 = 0, seg in bits 0..1
    scan_ifft_seg_kernel<<<Bdim*Cdim*2*8, 256, 0, stream>>>(bufB, bufA, pl, carry, st31);
    if (interleaved)
        fft_w_out1_kernel<1><<<32, 256, 0, stream>>>(st31, out1);
    else
        fft_w_out1_kernel<0><<<32, 256, 0, stream>>>(st31, out1);
    mix_mfma3_kernel<1><<<1024, 256, 0, stream>>>(bufA, nullptr, Apack, bc_re, bc_im, pl, out0pre, lnpart);
    ln_finish_kernel<<<64, 64, 0, stream>>>(lnpart, stats);
    ln_apply_kernel<<<8192, 256, 0, stream>>>(out0, out0pre, x, ln_w, ln_b, stats);
}

// Round 13
// 107.353 us; speedup vs baseline: 1.1989x; 1.1989x over previous
//
#include <hip/hip_runtime.h>
#include <cstdint>
#include <cstddef>

#define DEVINL __device__ __forceinline__

static constexpr int Bdim = 2, Ldim = 32, Cdim = 128, Hdim = 32, Wdim = 32;
static constexpr int HW  = Hdim * Wdim;         // 1024
static constexpr int CHW = Cdim * HW;           // 131072
static constexpr size_t OUT0_ELEMS = (size_t)Bdim * Ldim * CHW;  // 8388608
static constexpr size_t OUT1_CPLX  = (size_t)Bdim * CHW;         // 262144 complex elems

typedef __attribute__((ext_vector_type(8))) short short8v;   // 8 bf16 (4 VGPR)
typedef __attribute__((ext_vector_type(4))) float f32x4;     // MFMA C/D

DEVINL int bitrev5(int v) {
    return ((v&1)<<4) | ((v&2)<<2) | (v&4) | ((v&8)>>2) | ((v&16)>>4);
}
DEVINL unsigned short f2bf(float v) {               // RNE f32 -> bf16 bits
    unsigned u = __float_as_uint(v);
    return (unsigned short)((u + 0x7FFFu + ((u >> 16) & 1u)) >> 16);
}
DEVINL void bfsplit(float v, short& hi, short& lo) {
    unsigned short hb = f2bf(v);
    hi = (short)hb;
    float hf = __uint_as_float(((unsigned)hb) << 16);
    lo = (short)f2bf(v - hf);
}
DEVINL unsigned pack2bf(float2 v) {
    return (unsigned)f2bf(v.x) | ((unsigned)f2bf(v.y) << 16);
}
DEVINL float2 unpack2bf(unsigned u) {
    return make_float2(__uint_as_float(u << 16), __uint_as_float(u & 0xFFFF0000u));
}

// ================= 32-point radix-2 DIT FFT, fully in registers =================
template<int INV>
DEVINL void fft32_reg(float2 v[32]) {
    constexpr float TC[16] = { 1.0f, 0.980785280f, 0.923879533f, 0.831469612f,
                               0.707106781f, 0.555570233f, 0.382683432f, 0.195090322f,
                               0.0f, -0.195090322f, -0.382683432f, -0.555570233f,
                              -0.707106781f, -0.831469612f, -0.923879533f, -0.980785280f };
    constexpr float TS[16] = { 0.0f, -0.195090322f, -0.382683432f, -0.555570233f,
                              -0.707106781f, -0.831469612f, -0.923879533f, -0.980785280f,
                              -1.0f, -0.980785280f, -0.923879533f, -0.831469612f,
                              -0.707106781f, -0.555570233f, -0.382683432f, -0.195090322f };
#pragma unroll
    for (int st = 0; st < 5; ++st) {
        const int half = 1 << st;
#pragma unroll
        for (int bf = 0; bf < 16; ++bf) {
            const int g = bf >> st;
            const int j = bf & (half - 1);
            const int i0 = (g << (st+1)) + j;
            const float wr = TC[j << (4-st)];
            const float wi = INV ? -TS[j << (4-st)] : TS[j << (4-st)];
            float2 a0 = v[i0], a1 = v[i0+half];
            float tr = wr*a1.x - wi*a1.y;
            float ti = wr*a1.y + wi*a1.x;
            v[i0]      = make_float2(a0.x+tr, a0.y+ti);
            v[i0+half] = make_float2(a0.x-tr, a0.y-ti);
        }
    }
}

// ---- forward FFT along H (real f32 input) -> plain bf16x2 [b][l][c][hf][w] ----
__global__ __launch_bounds__(256) void fft_h_fwd_bf_kernel(const float* __restrict__ x,
                                                           unsigned* __restrict__ Hf) {
    const int gid = blockIdx.x*256 + threadIdx.x;     // 0..262143
    const int w = gid & 31;
    const size_t slice = (size_t)(gid >> 5);          // (b,l,c)
    const float* src = x + slice*HW + w;
    float2 v[32];
#pragma unroll
    for (int i = 0; i < 32; ++i)
        v[i] = make_float2(src[(size_t)bitrev5(i)*Wdim], 0.f);
    fft32_reg<0>(v);
    unsigned* dst = Hf + slice*HW + w;
#pragma unroll
    for (int h = 0; h < 32; ++h) dst[(size_t)h*Wdim] = pack2bf(v[h]);
}

// ---- inverse FFT along H (bf16x2 in -> bf16x2 out, scale 1/32) ----
__global__ __launch_bounds__(256) void ifft_h_bf_kernel(const unsigned* __restrict__ Sin,
                                                        unsigned* __restrict__ Ysp) {
    const int gid = blockIdx.x*256 + threadIdx.x;     // 0..262143
    const int w = gid & 31;
    const size_t slice = (size_t)(gid >> 5);          // (b,l,c)
    const unsigned* src = Sin + slice*HW + w;
    float2 v[32];
#pragma unroll
    for (int i = 0; i < 32; ++i)
        v[i] = unpack2bf(src[(size_t)bitrev5(i)*Wdim]);
    fft32_reg<1>(v);
    const float sc = 1.0f / 32.0f;
    unsigned* dst = Ysp + slice*HW + w;
#pragma unroll
    for (int h = 0; h < 32; ++h)
        dst[(size_t)h*Wdim] = pack2bf(make_float2(v[h].x*sc, v[h].y*sc));
}

// ---- forward FFT along W for out1 (l=31 freq state, f32) ----
template<int CPLX>
__global__ __launch_bounds__(256) void fft_w_out1_kernel(const float2* __restrict__ st31,
                                                         float* __restrict__ out1) {
    const int row = blockIdx.x*256 + threadIdx.x;   // 0..8191 = (b,c,h)
    const float2* src = st31 + (size_t)row*32;
    float2 v[32];
#pragma unroll
    for (int i = 0; i < 32; ++i) v[i] = src[bitrev5(i)];
    fft32_reg<0>(v);
    if (CPLX) {
        float2* dst = reinterpret_cast<float2*>(out1) + (size_t)row*32;
#pragma unroll
        for (int i = 0; i < 32; ++i) dst[i] = v[i];
    } else {
        float* dst = out1 + (size_t)row*32;
#pragma unroll
        for (int i = 0; i < 32; ++i) dst[i] = v[i].x;
    }
}

// ======================= A-pack (unchanged, verified) ==========
__global__ __launch_bounds__(256) void pack_w_kernel(
    const float* __restrict__ Wb_re, const float* __restrict__ Wb_im,
    const float* __restrict__ Wc_re, const float* __restrict__ Wc_im,
    short* __restrict__ Apack)
{
    const int gid = blockIdx.x*256 + threadIdx.x;    // 0..12287
    const int a    = gid >> 12;
    const int rem  = gid & 4095;
    const int f    = rem >> 6;
    const int lane = rem & 63;
    const int m  = f >> 3, kc = f & 7;
    const int row = m*16 + (lane & 15);
    const int kbase = kc*32 + ((lane >> 4) << 3);
    short8v hi8, lo8;
#pragma unroll
    for (int j = 0; j < 8; ++j) {
        const int k = kbase + j;
        const int half = k >> 7;
        const int c = k & 127;
        float v;
        if (a == 0)      v = half ? -Wb_im[row*Cdim + c] : Wb_re[row*Cdim + c];
        else if (a == 1) v = half ?  Wb_re[row*Cdim + c] : Wb_im[row*Cdim + c];
        else             v = half ? -Wc_im[row*Cdim + c] : Wc_re[row*Cdim + c];
        short h, l; bfsplit(v, h, l);
        hi8[j] = h; lo8[j] = l;
    }
    const size_t off = (size_t)(f*64 + lane)*8;
    *reinterpret_cast<short8v*>(Apack + (size_t)(2*a)  *32768 + off) = hi8;
    *reinterpret_cast<short8v*>(Apack + (size_t)(2*a+1)*32768 + off) = lo8;
}

// ======================= MFMA channel mix v3: plain bf16x2 input (verified r9) ====
template<int MODE>
__global__ __launch_bounds__(256) void mix_mfma3_kernel(
    const unsigned* __restrict__ Yin,
    unsigned* __restrict__ Sout,
    const short* __restrict__ Apack,
    const float* __restrict__ bre, const float* __restrict__ bim,
    const float* __restrict__ pl,
    unsigned short* __restrict__ outr,
    float2* __restrict__ lnpart)
{
    __shared__ short Bs[8][4][64][8];    // 32 KB
    const int bx = blockIdx.x;           // 64 bl * 16 tt
    const int bl = bx >> 4, tt = bx & 15;
    const int t = threadIdx.x;
    const int wv = t >> 6, lane = t & 63;

    // ---- stage: coalesced loads + lo/hi de-interleave into fragments ----
    const unsigned* src = Yin + (size_t)bl*CHW + tt*64;
#pragma unroll
    for (int g = 0; g < 4; ++g) {
        const int id = g*256 + t;          // 1024 groups of 8 channels
        const int hw = id & 63;
        const int co = id >> 6;            // channel octet 0..15 (c = co*8+j)
        const int kc = co >> 2;
        const int ln = (co & 3)*16 + (hw & 15);
        const int nt4 = hw >> 4;
        unsigned u[8];
#pragma unroll
        for (int j = 0; j < 8; ++j)
            u[j] = src[(size_t)(co*8 + j)*HW + hw];
        unsigned re[4], im[4];
#pragma unroll
        for (int p = 0; p < 4; ++p) {
            re[p] = (u[2*p] & 0xFFFFu) | (u[2*p+1] << 16);
            im[p] = (u[2*p] >> 16) | (u[2*p+1] & 0xFFFF0000u);
        }
        *reinterpret_cast<uint4*>(&Bs[kc][nt4][ln][0])   = make_uint4(re[0], re[1], re[2], re[3]);
        *reinterpret_cast<uint4*>(&Bs[kc+4][nt4][ln][0]) = make_uint4(im[0], im[1], im[2], im[3]);
    }
    __syncthreads();

    f32x4 accRe[2][4];
    f32x4 accIm[2][4];
#pragma unroll
    for (int mi = 0; mi < 2; ++mi)
#pragma unroll
        for (int nt = 0; nt < 4; ++nt) {
            accRe[mi][nt] = (f32x4)(0.0f);
            accIm[mi][nt] = (f32x4)(0.0f);
        }

    const short* Are_hi = Apack + (MODE == 0 ? 0 : 4)*32768;
    const short* Are_lo = Are_hi + 32768;
    const short* Aim_hi = Apack + 2*32768;   // MODE 0 only
    const short* Aim_lo = Aim_hi + 32768;

#pragma unroll 2
    for (int kc = 0; kc < 8; ++kc) {
        short8v bh[4];
#pragma unroll
        for (int nt = 0; nt < 4; ++nt)
            bh[nt] = *reinterpret_cast<const short8v*>(&Bs[kc][nt][lane][0]);
#pragma unroll
        for (int mi = 0; mi < 2; ++mi) {
            const int m = wv*2 + mi;
            const size_t off = (size_t)((m*8 + kc)*64 + lane)*8;
            const short8v arh = *reinterpret_cast<const short8v*>(Are_hi + off);
            const short8v arl = *reinterpret_cast<const short8v*>(Are_lo + off);
#pragma unroll
            for (int nt = 0; nt < 4; ++nt) {
                accRe[mi][nt] = __builtin_amdgcn_mfma_f32_16x16x32_bf16(arh, bh[nt], accRe[mi][nt], 0, 0, 0);
                accRe[mi][nt] = __builtin_amdgcn_mfma_f32_16x16x32_bf16(arl, bh[nt], accRe[mi][nt], 0, 0, 0);
            }
            if (MODE == 0) {
                const short8v aih = *reinterpret_cast<const short8v*>(Aim_hi + off);
                const short8v ail = *reinterpret_cast<const short8v*>(Aim_lo + off);
#pragma unroll
                for (int nt = 0; nt < 4; ++nt) {
                    accIm[mi][nt] = __builtin_amdgcn_mfma_f32_16x16x32_bf16(aih, bh[nt], accIm[mi][nt], 0, 0, 0);
                    accIm[mi][nt] = __builtin_amdgcn_mfma_f32_16x16x32_bf16(ail, bh[nt], accIm[mi][nt], 0, 0, 0);
                }
            }
        }
    }

    // ---- epilogue.  D layout: col = lane&15, row = (lane>>4)*4 + r ----
    const int col   = lane & 15;
    const int rbase = (lane >> 4) * 4;
    float lns = 0.f, lnq = 0.f;
#pragma unroll
    for (int mi = 0; mi < 2; ++mi) {
#pragma unroll
        for (int r = 0; r < 4; ++r) {
            const int o = wv*32 + mi*16 + rbase + r;
            if (MODE == 0) {
                const float br = bre[o], bi = bim[o];
                const float g0 = expf(pl[(2*Cdim + o)*Hdim + 2*tt]);
                const float g1 = expf(pl[(2*Cdim + o)*Hdim + 2*tt + 1]);
#pragma unroll
                for (int nt = 0; nt < 4; ++nt) {
                    const int wcol = nt*16 + col;
                    const float g = (nt < 2) ? g0 : g1;
                    const float bsel = ((wcol & 31) == 0) ? 1.0f : 0.0f;
                    float2 rv;
                    rv.x = (accRe[mi][nt][r] + br*bsel) * g;
                    rv.y = (accIm[mi][nt][r] + bi*bsel) * g;
                    Sout[(size_t)bl*CHW + (size_t)o*HW + tt*64 + wcol] = pack2bf(rv);
                }
            } else {
                const float br = bre[o];
#pragma unroll
                for (int nt = 0; nt < 4; ++nt) {
                    const int wcol = nt*16 + col;
                    const float v = accRe[mi][nt][r] + br;
                    outr[(size_t)bl*CHW + (size_t)o*HW + tt*64 + wcol] = f2bf(v);
                    lns += v; lnq += v*v;
                }
            }
        }
    }
    if (MODE == 1) {
#pragma unroll
        for (int off = 32; off > 0; off >>= 1) {
            lns += __shfl_down(lns, off);
            lnq += __shfl_down(lnq, off);
        }
        __shared__ float2 red[4];
        if (lane == 0) red[wv] = make_float2(lns, lnq);
        __syncthreads();
        if (t == 0) {
            float2 a = red[0], b2 = red[1], c2 = red[2], d = red[3];
            lnpart[bx] = make_float2(a.x + b2.x + c2.x + d.x, a.y + b2.y + c2.y + d.y);
        }
    }
}

// ======================= scan over L (bf16x2 in/out, f32 state; verified r8) ======
__global__ __launch_bounds__(256) void scan_kernel(
    unsigned* __restrict__ Hf2, const float* __restrict__ pl, float2* __restrict__ st31)
{
    const int idx = blockIdx.x*256 + threadIdx.x;   // 0..262143 = B*C*H*W
    const int b   = idx >> 17;
    const int chw = idx & (CHW - 1);
    const int c   = chw >> 10;
    const int h   = (chw >> 5) & 31;
    const float nu = expf(pl[c*Hdim + h]);
    const float th = expf(pl[(Cdim + c)*Hdim + h]);
    const float rr = expf(-nu);
    const float lr = rr * cosf(th);
    const float li = rr * sinf(th);
    float2 y = make_float2(0.f, 0.f);
    const size_t basei = (size_t)b * Ldim * CHW + chw;
#pragma unroll 4
    for (int l = 0; l < Ldim; ++l) {
        float2 hv = unpack2bf(Hf2[basei + (size_t)l*CHW]);
        float yr = fmaf(lr, y.x, fmaf(-li, y.y, hv.x));
        float yi = fmaf(lr, y.y, fmaf( li, y.x, hv.y));
        y = make_float2(yr, yi);
        Hf2[basei + (size_t)l*CHW] = pack2bf(y);
    }
    st31[(size_t)b*CHW + chw] = y;
}

// ======================= LayerNorm finish + apply =======================
__global__ __launch_bounds__(64) void ln_finish_kernel(const float2* __restrict__ lnpart,
                                                       float2* __restrict__ stats) {
    const int bl = blockIdx.x;
    const int t = threadIdx.x;
    float s = 0.f, sq = 0.f;
    if (t < 16) { float2 v = lnpart[bl*16 + t]; s = v.x; sq = v.y; }
#pragma unroll
    for (int off = 8; off > 0; off >>= 1) {
        s  += __shfl_down(s, off);
        sq += __shfl_down(sq, off);
    }
    if (t == 0) {
        const float invN = 1.0f / (float)CHW;
        float mean = s * invN;
        float var  = sq * invN - mean*mean;
        stats[bl] = make_float2(mean, rsqrtf(var + 1e-5f));
    }
}

__global__ __launch_bounds__(256) void ln_apply_kernel(
    float* __restrict__ out0, const unsigned short* __restrict__ hpre,
    const float* __restrict__ x,
    const float* __restrict__ lnw, const float* __restrict__ lnb,
    const float2* __restrict__ stats)
{
    const int idx4 = blockIdx.x*256 + threadIdx.x;   // 4 elems per thread
    const int i = idx4 * 4;
    const int bl = i >> 17;
    const int chw4 = (i & (CHW - 1)) >> 2;
    const float2 st = stats[bl];
    const uint2 hu = reinterpret_cast<const uint2*>(hpre)[idx4];
    float4 h;
    h.x = __uint_as_float(hu.x << 16);
    h.y = __uint_as_float(hu.x & 0xFFFF0000u);
    h.z = __uint_as_float(hu.y << 16);
    h.w = __uint_as_float(hu.y & 0xFFFF0000u);
    float4 xv = reinterpret_cast<const float4*>(x)[idx4];
    float4 w  = reinterpret_cast<const float4*>(lnw)[chw4];
    float4 bb = reinterpret_cast<const float4*>(lnb)[chw4];
    const float m = st.x, rs = st.y;
    float4 r;
    r.x = fmaf((h.x - m)*rs, w.x, bb.x) + xv.x;
    r.y = fmaf((h.y - m)*rs, w.y, bb.y) + xv.y;
    r.z = fmaf((h.z - m)*rs, w.z, bb.z) + xv.z;
    r.w = fmaf((h.w - m)*rs, w.w, bb.w) + xv.w;
    reinterpret_cast<float4*>(out0)[idx4] = r;
}

// ======================= launch =======================
extern "C" void kernel_launch(void* const* d_in, const int* in_sizes, int n_in,
                              void* d_out, int out_size, void* d_ws, size_t ws_size,
                              hipStream_t stream)
{
    const float* x     = (const float*)d_in[0];
    const float* pl    = (const float*)d_in[1];
    const float* Wb_re = (const float*)d_in[2];
    const float* Wb_im = (const float*)d_in[3];
    const float* bb_re = (const float*)d_in[4];
    const float* bb_im = (const float*)d_in[5];
    const float* Wc_re = (const float*)d_in[6];
    const float* Wc_im = (const float*)d_in[7];
    const float* bc_re = (const float*)d_in[8];
    const float* bc_im = (const float*)d_in[9];
    const float* ln_w  = (const float*)d_in[10];
    const float* ln_b  = (const float*)d_in[11];

    float* out0 = (float*)d_out;
    float* out1 = out0 + OUT0_ELEMS;

    // workspace layout (~86.4 MB; rounds 7-12 proved ws >= 103 MB)
    char* ws = (char*)d_ws;
    unsigned*       bufA    = (unsigned*)       ws;                        // 33,554,432 (Hf_freq, later Ysp)
    unsigned*       bufB    = (unsigned*)       (ws + 33554432);           // 33,554,432 (scan in/out)
    unsigned short* out0pre = (unsigned short*) (ws + 67108864);           // 16,777,216
    float2*         st31    = (float2*)         (ws + 83886080);           //  2,097,152
    short*          Apack   = (short*)          (ws + 85983232);           //    393,216
    float2*         lnpart  = (float2*)         (ws + 86376448);           //      8,192
    float2*         stats   = (float2*)         (ws + 86384640);           //        512

    const bool interleaved = ((size_t)out_size >= OUT0_ELEMS + 2*OUT1_CPLX);

    pack_w_kernel<<<48, 256, 0, stream>>>(Wb_re, Wb_im, Wc_re, Wc_im, Apack);
    fft_h_fwd_bf_kernel<<<1024, 256, 0, stream>>>(x, bufA);
    mix_mfma3_kernel<0><<<1024, 256, 0, stream>>>(bufA, bufB, Apack, bb_re, bb_im, pl, nullptr, nullptr);
    scan_kernel<<<1024, 256, 0, stream>>>(bufB, pl, st31);
    if (interleaved)
        fft_w_out1_kernel<1><<<32, 256, 0, stream>>>(st31, out1);
    else
        fft_w_out1_kernel<0><<<32, 256, 0, stream>>>(st31, out1);
    ifft_h_bf_kernel<<<1024, 256, 0, stream>>>(bufB, bufA);
    mix_mfma3_kernel<1><<<1024, 256, 0, stream>>>(bufA, nullptr, Apack, bc_re, bc_im, pl, out0pre, lnpart);
    ln_finish_kernel<<<64, 64, 0, stream>>>(lnpart, stats);
    ln_apply_kernel<<<8192, 256, 0, stream>>>(out0, out0pre, x, ln_w, ln_b, stats);
}